// Round 2
// baseline (277.873 us; speedup 1.0000x reference)
//
#include <hip/hip_runtime.h>
#include <hip/hip_fp16.h>

#define NTHREADS 256

__device__ __forceinline__ int reflect128(int p) {
    p = (p < 0) ? (-p - 1) : p;
    p = (p >= 128) ? (255 - p) : p;
    return p;
}

// Per output phase j: 3 consecutive nonzero taps out of 5.
// cc0/cs0 apply to the G0-pair source (Yl or lh), cc1/cs1 to the G1-pair (hl or hh).
__constant__ int   cs0[4] = {2, 1, 1, 0};
__constant__ int   cs1[4] = {1, 2, 0, 1};
__constant__ float cc0[4][3] = {
    { 0.760272369066126f, -0.0883294244510729f,  0.0351638365171441f},
    { 0.233890320607236f,  0.587518297723561f,  -0.114301837144249f},
    {-0.114301837144249f,  0.587518297723561f,   0.233890320607236f},
    { 0.0351638365171441f, -0.0883294244510729f, 0.760272369066126f}};
__constant__ float cc1[4][3] = {
    { 0.233890320607236f,  0.587518297723561f,  -0.114301837144249f},
    {-0.760272369066126f,  0.0883294244510729f, -0.0351638365171441f},
    {-0.0351638365171441f, 0.0883294244510729f, -0.760272369066126f},
    {-0.114301837144249f,  0.587518297723561f,   0.233890320607236f}};

__global__ __launch_bounds__(NTHREADS, 6)
void dtcwt_inv_kernel(const float* __restrict__ Yl,
                      const float* __restrict__ Yhr,
                      const float* __restrict__ Yhi,
                      float* __restrict__ out)
{
    const int tid = threadIdx.x;

    // XCD-aware swizzle: assuming round-robin bid%8 -> XCD, give each XCD a
    // contiguous run of blocks = whole planes, so a plane's 16 tiles share one L2.
    const int bid  = blockIdx.x;
    const int perx = gridDim.x >> 3;               // blocks per XCD (grid % 8 == 0)
    const int gidx = (bid & 7) * perx + (bid >> 3);
    const int plane = gidx >> 4;                   // 0..511
    const int tile  = gidx & 15;
    const int ct = tile & 3;                       // col tile 0..3
    const int rt = tile >> 2;                      // row tile 0..3

    const int OR0 = rt * 64, OC0 = ct * 64;
    const int i0r = OR0 >> 2, i0c = OC0 >> 2;
    const int yrb = 2 * i0r - 4;    // raw first y row of the 40-row window (even)
    const int icb = 2 * i0c - 4;    // raw first input col of the 40-col window (even)

    const float* yl = Yl + (size_t)plane * (128 * 128);
    const float* hr = Yhr + (size_t)plane * 6 * 4096;
    const float* hi = Yhi + (size_t)plane * 6 * 4096;

    // Transposed f16 staging: sT[arr][u][t], u = input column, t = input row.
    // u-row stride = 40 halves = 80 B (16B-aligned => ds_read_b128 on contiguous t).
    // arr: 0 = Yl, 1 = Lh, 2 = Hl, 3 = Hh.  Total 12.8 KB.
    __shared__ __align__(16) __half sT[4][40][40];

    const float RS2 = 0.70710678118654752440f;  // 1/sqrt(2)

    // ---- Phase A1: stage Yl window transposed, packing t-pairs into half2 ----
    for (int e = tid; e < 800; e += NTHREADS) {
        const int t2 = e / 40;                 // t-pair index 0..19
        const int u  = e - t2 * 40;            // 0..39 (fastest -> coalesced global)
        const int cg = reflect128(icb + u);
        const int ra = reflect128(yrb + 2 * t2);
        const int rb = reflect128(yrb + 2 * t2 + 1);
        const __half2 hv = __halves2half2(__float2half(yl[ra * 128 + cg]),
                                          __float2half(yl[rb * 128 + cg]));
        *(__half2*)&sT[0][u][2 * t2] = hv;
    }

    // ---- Phase A2: c2q per 2x2 quad; 12 global loads -> 12 staged halves ----
    for (int e = tid; e < 400; e += NTHREADS) {
        const int t2 = e / 20;
        const int u2 = e - t2 * 20;
        const int ar = i0r - 2 + t2;
        const int ac = i0c - 2 + u2;
        const int oobr = (ar < 0) | (ar >= 64);
        const int oobc = (ac < 0) | (ac >= 64);
        const int r2 = oobr ? ((ar < 0) ? (-ar - 1) : (127 - ar)) : ar;
        const int c2 = oobc ? ((ac < 0) ? (-ac - 1) : (127 - ac)) : ac;
        const int off = r2 * 64 + c2;
        const float ar0 = hr[off], ar1 = hr[4096 + off], ar2 = hr[2 * 4096 + off];
        const float ar3 = hr[3 * 4096 + off], ar4 = hr[4 * 4096 + off], ar5 = hr[5 * 4096 + off];
        const float ai0 = hi[off], ai1 = hi[4096 + off], ai2 = hi[2 * 4096 + off];
        const float ai3 = hi[3 * 4096 + off], ai4 = hi[4 * 4096 + off], ai5 = hi[5 * 4096 + off];
#pragma unroll
        for (int du = 0; du < 2; ++du) {
            const int q = du ^ oobc;
            __half lh[2], hl[2], hh[2];
#pragma unroll
            for (int dt = 0; dt < 2; ++dt) {
                const int p = dt ^ oobr;            // reflection flips sample parity
                const float sA = (p & q) ? -RS2 : RS2;
                const float sB = (p & (q ^ 1)) ? -RS2 : RS2;
                float b0, b5, b2v, b3, b1, b4;
                if (p == q) { b0 = ar0; b5 = ar5; b2v = ar2; b3 = ar3; b1 = ar1; b4 = ar4; }
                else        { b0 = ai0; b5 = ai5; b2v = ai2; b3 = ai3; b1 = ai1; b4 = ai4; }
                lh[dt] = __float2half(sA * b0 + sB * b5);
                hl[dt] = __float2half(sA * b2v + sB * b3);
                hh[dt] = __float2half(sA * b1 + sB * b4);
            }
            const int u = 2 * u2 + du, t0 = 2 * t2;
            *(__half2*)&sT[1][u][t0] = __halves2half2(lh[0], lh[1]);
            *(__half2*)&sT[2][u][t0] = __halves2half2(hl[0], hl[1]);
            *(__half2*)&sT[3][u][t0] = __halves2half2(hh[0], hh[1]);
        }
    }
    __syncthreads();

    // ---- Phase B+C fused: thread owns one column + 16-row output strip.
    //      Row filter reads contiguous-t f16 via ds_read_b128 into registers. ----
    const int c  = tid & 63;        // output column within tile
    const int g  = tid >> 6;        // 16-row output strip
    const int jc = c & 3;
    const int q2 = c >> 2;
    const int ub0 = 2 * q2 + (jc & 1) + 2 * cs0[jc];          // first G0 tap col (u)
    const int ub1 = 2 * q2 + ((jc & 1) ^ 1) + 2 * cs1[jc];    // first G1 tap col

    union H16 { float4 v[2]; __half h[16]; };
    float y1v[14], y2v[14];
#pragma unroll
    for (int k = 0; k < 14; ++k) { y1v[k] = 0.0f; y2v[k] = 0.0f; }

#pragma unroll
    for (int d = 0; d < 3; ++d) {
        const float ad = cc0[jc][d];
        const float bd = cc1[jc][d];
        const int u0 = ub0 + 2 * d;
        const int u1 = ub1 + 2 * d;
        H16 xa, xb, xc, xd;
        const float4* pa = (const float4*)&sT[0][u0][8 * g];  // Yl  -> y1, G0
        const float4* pb = (const float4*)&sT[2][u1][8 * g];  // Hl  -> y1, G1
        const float4* pc = (const float4*)&sT[1][u0][8 * g];  // Lh  -> y2, G0
        const float4* pd = (const float4*)&sT[3][u1][8 * g];  // Hh  -> y2, G1
        xa.v[0] = pa[0]; xa.v[1] = pa[1];
        xb.v[0] = pb[0]; xb.v[1] = pb[1];
        xc.v[0] = pc[0]; xc.v[1] = pc[1];
        xd.v[0] = pd[0]; xd.v[1] = pd[1];
#pragma unroll
        for (int k = 0; k < 14; ++k) {
            y1v[k] += __half2float(xa.h[k + 1]) * ad + __half2float(xb.h[k + 1]) * bd;
            y2v[k] += __half2float(xc.h[k + 1]) * ad + __half2float(xd.h[k + 1]) * bd;
        }
    }

    float* op = out + ((size_t)plane * 256 + OR0 + 16 * g) * 256 + OC0 + c;
#pragma unroll
    for (int j = 0; j < 4; ++j) {
        const int p0 = j & 1, p1 = p0 ^ 1;
        const int r0 = p0 + 2 * cs0[j];   // y1 tap rows: 2m + r0 + {0,2,4}
        const int r1 = p1 + 2 * cs1[j];
        const float d0 = cc0[j][0], d1 = cc0[j][1], d2 = cc0[j][2];
        const float e0 = cc1[j][0], e1 = cc1[j][1], e2 = cc1[j][2];
#pragma unroll
        for (int mm = 0; mm < 4; ++mm) {
            const int k0 = 2 * mm + r0 - 1;
            const int k1 = 2 * mm + r1 - 1;
            const float acc = y1v[k0] * d0 + y1v[k0 + 2] * d1 + y1v[k0 + 4] * d2
                            + y2v[k1] * e0 + y2v[k1 + 2] * e1 + y2v[k1 + 4] * e2;
            op[(size_t)(4 * mm + j) * 256] = acc;
        }
    }
}

extern "C" void kernel_launch(void* const* d_in, const int* in_sizes, int n_in,
                              void* d_out, int out_size, void* d_ws, size_t ws_size,
                              hipStream_t stream) {
    const float* Yl  = (const float*)d_in[0];
    const float* Yhr = (const float*)d_in[1];
    const float* Yhi = (const float*)d_in[2];
    float* out = (float*)d_out;

    const int planes = in_sizes[0] / (128 * 128);   // B*C = 512
    dim3 grid(planes * 16, 1, 1);
    dtcwt_inv_kernel<<<grid, NTHREADS, 0, stream>>>(Yl, Yhr, Yhi, out);
}

// Round 3
// 259.856 us; speedup vs baseline: 1.0693x; 1.0693x over previous
//
#include <hip/hip_runtime.h>

#define NTHREADS 256

__device__ __forceinline__ int reflect128(int p) {
    p = (p < 0) ? (-p - 1) : p;
    p = (p >= 128) ? (255 - p) : p;
    return p;
}

// Per output phase j: 3 consecutive nonzero taps out of 5.
// cc0/cs0 apply to the G0-pair source (Yl or lh), cc1/cs1 to the G1-pair (hl or hh).
__constant__ int   cs0[4] = {2, 1, 1, 0};
__constant__ int   cs1[4] = {1, 2, 0, 1};
__constant__ float cc0[4][3] = {
    { 0.760272369066126f, -0.0883294244510729f,  0.0351638365171441f},
    { 0.233890320607236f,  0.587518297723561f,  -0.114301837144249f},
    {-0.114301837144249f,  0.587518297723561f,   0.233890320607236f},
    { 0.0351638365171441f, -0.0883294244510729f, 0.760272369066126f}};
__constant__ float cc1[4][3] = {
    { 0.233890320607236f,  0.587518297723561f,  -0.114301837144249f},
    {-0.760272369066126f,  0.0883294244510729f, -0.0351638365171441f},
    {-0.0351638365171441f, 0.0883294244510729f, -0.760272369066126f},
    {-0.114301837144249f,  0.587518297723561f,   0.233890320607236f}};

__global__ __launch_bounds__(NTHREADS, 6)
void dtcwt_inv_kernel(const float* __restrict__ Yl,
                      const float* __restrict__ Yhr,
                      const float* __restrict__ Yhi,
                      float* __restrict__ out)
{
    const int tid = threadIdx.x;

    // XCD-aware swizzle (kept from round 2: FETCH 224->66 MB). Each XCD gets a
    // contiguous run of gidx = whole planes, so a plane's 16 tiles share one L2.
    const int bid  = blockIdx.x;
    const int perx = gridDim.x >> 3;               // blocks per XCD (grid % 8 == 0)
    const int gidx = (bid & 7) * perx + (bid >> 3);
    const int plane = gidx >> 4;                   // 0..511
    const int tile  = gidx & 15;
    const int ct = tile & 3;                       // col tile 0..3
    const int rt = tile >> 2;                      // row tile 0..3

    const int OR0 = rt * 64, OC0 = ct * 64;
    const int i0r = OR0 >> 2, i0c = OC0 >> 2;
    const int yrb = 2 * i0r - 4;    // raw first y row of the 40-row window (even)
    const int icb = 2 * i0c - 4;    // raw first input col of the 40-col window (even)

    const float* yl = Yl + (size_t)plane * (128 * 128);
    const float* hr = Yhr + (size_t)plane * 6 * 4096;
    const float* hi = Yhi + (size_t)plane * 6 * 4096;

    // Packed-by-read-offset staging (f32, natural order):
    //   sP[t][u] = (Yl, Lh)  -- both read at u-offset ub0 (G0 taps)
    //   sQ[t][u] = (Hl, Hh)  -- both read at u-offset ub1 (G1 taps)
    // y1 takes .x of both, y2 takes .y of both -> 6 float2 loads per row
    // (ds_read2_b64-mergeable) instead of 12 scalar loads.
    __shared__ float2 sP[40][40];
    __shared__ float2 sQ[40][40];

    const float RS2 = 0.70710678118654752440f;  // 1/sqrt(2)

    // ---- Phase A1: stage Yl window (40x40, reflected) into sP.x ----
    for (int e = tid; e < 1600; e += NTHREADS) {
        const int t = e / 40;
        const int u = e - t * 40;
        const int r2 = reflect128(yrb + t);
        const int c2 = reflect128(icb + u);
        sP[t][u].x = yl[r2 * 128 + c2];
    }

    // ---- Phase A2: c2q per 2x2 quad; 12 global loads -> 12 staged values ----
    for (int e = tid; e < 400; e += NTHREADS) {
        const int t2 = e / 20;
        const int u2 = e - t2 * 20;
        const int ar = i0r - 2 + t2;
        const int ac = i0c - 2 + u2;
        const int oobr = (ar < 0) | (ar >= 64);
        const int oobc = (ac < 0) | (ac >= 64);
        const int r2 = oobr ? ((ar < 0) ? (-ar - 1) : (127 - ar)) : ar;
        const int c2 = oobc ? ((ac < 0) ? (-ac - 1) : (127 - ac)) : ac;
        const int off = r2 * 64 + c2;
        const float ar0 = hr[off], ar1 = hr[4096 + off], ar2 = hr[2 * 4096 + off];
        const float ar3 = hr[3 * 4096 + off], ar4 = hr[4 * 4096 + off], ar5 = hr[5 * 4096 + off];
        const float ai0 = hi[off], ai1 = hi[4096 + off], ai2 = hi[2 * 4096 + off];
        const float ai3 = hi[3 * 4096 + off], ai4 = hi[4 * 4096 + off], ai5 = hi[5 * 4096 + off];
#pragma unroll
        for (int dt = 0; dt < 2; ++dt) {
#pragma unroll
            for (int du = 0; du < 2; ++du) {
                const int p = dt ^ oobr;            // reflection flips sample parity
                const int q = du ^ oobc;
                const float sA = (p & q) ? -RS2 : RS2;
                const float sB = (p & (q ^ 1)) ? -RS2 : RS2;
                float b0, b5, b2v, b3, b1, b4;
                if (p == q) { b0 = ar0; b5 = ar5; b2v = ar2; b3 = ar3; b1 = ar1; b4 = ar4; }
                else        { b0 = ai0; b5 = ai5; b2v = ai2; b3 = ai3; b1 = ai1; b4 = ai4; }
                const int t = 2 * t2 + dt, u = 2 * u2 + du;
                sP[t][u].y = sA * b0 + sB * b5;                          // Lh
                sQ[t][u]   = make_float2(sA * b2v + sB * b3,             // Hl
                                         sA * b1 + sB * b4);             // Hh
            }
        }
    }
    __syncthreads();

    // ---- Phase B+C fused: thread owns one column + 16-row output strip.
    //      Row-filter its 14-row y1/y2 window into registers, then column-filter. ----
    const int c  = tid & 63;        // output column within tile
    const int g  = tid >> 6;        // 16-row output strip
    const int jc = c & 3;
    const int q2 = c >> 2;
    const float a0  = cc0[jc][0], a1  = cc0[jc][1], a2  = cc0[jc][2];
    const float b0w = cc1[jc][0], b1w = cc1[jc][1], b2w = cc1[jc][2];
    const int ub0 = 2 * q2 + (jc & 1) + 2 * cs0[jc];          // first G0 tap col (u)
    const int ub1 = 2 * q2 + ((jc & 1) ^ 1) + 2 * cs1[jc];    // first G1 tap col

    const int tb = 8 * g;           // y rows needed: [tb+1, tb+14]
    float y1v[14], y2v[14];
#pragma unroll
    for (int k = 0; k < 14; ++k) {
        const int t = tb + 1 + k;
        const float2 P0 = sP[t][ub0], P1 = sP[t][ub0 + 2], P2 = sP[t][ub0 + 4];
        const float2 Q0 = sQ[t][ub1], Q1 = sQ[t][ub1 + 2], Q2 = sQ[t][ub1 + 4];
        y1v[k] = P0.x * a0  + P1.x * a1  + P2.x * a2
               + Q0.x * b0w + Q1.x * b1w + Q2.x * b2w;
        y2v[k] = P0.y * a0  + P1.y * a1  + P2.y * a2
               + Q0.y * b0w + Q1.y * b1w + Q2.y * b2w;
    }

    float* op = out + ((size_t)plane * 256 + OR0 + 16 * g) * 256 + OC0 + c;
#pragma unroll
    for (int j = 0; j < 4; ++j) {
        const int p0 = j & 1, p1 = p0 ^ 1;
        const int r0 = p0 + 2 * cs0[j];   // y1 tap rows: 2m + r0 + {0,2,4}
        const int r1 = p1 + 2 * cs1[j];
        const float d0 = cc0[j][0], d1 = cc0[j][1], d2 = cc0[j][2];
        const float e0 = cc1[j][0], e1 = cc1[j][1], e2 = cc1[j][2];
#pragma unroll
        for (int mm = 0; mm < 4; ++mm) {
            const int k0 = 2 * mm + r0 - 1;
            const int k1 = 2 * mm + r1 - 1;
            const float acc = y1v[k0] * d0 + y1v[k0 + 2] * d1 + y1v[k0 + 4] * d2
                            + y2v[k1] * e0 + y2v[k1 + 2] * e1 + y2v[k1 + 4] * e2;
            op[(size_t)(4 * mm + j) * 256] = acc;
        }
    }
}

extern "C" void kernel_launch(void* const* d_in, const int* in_sizes, int n_in,
                              void* d_out, int out_size, void* d_ws, size_t ws_size,
                              hipStream_t stream) {
    const float* Yl  = (const float*)d_in[0];
    const float* Yhr = (const float*)d_in[1];
    const float* Yhi = (const float*)d_in[2];
    float* out = (float*)d_out;

    const int planes = in_sizes[0] / (128 * 128);   // B*C = 512
    dim3 grid(planes * 16, 1, 1);
    dtcwt_inv_kernel<<<grid, NTHREADS, 0, stream>>>(Yl, Yhr, Yhi, out);
}